// Round 1
// baseline (611.161 us; speedup 1.0000x reference)
//
#include <hip/hip_runtime.h>
#include <hip/hip_fp16.h>
#include <stdint.h>

typedef _Float16 f16;
typedef _Float16 f16x8 __attribute__((ext_vector_type(8)));
typedef float f32x4 __attribute__((ext_vector_type(4)));

#define T_STEPS 200

#define MFMA16(a,b,c) __builtin_amdgcn_mfma_f32_16x16x32_f16((a),(b),(c),0,0,0)

__device__ __forceinline__ f16x8 cvt_f16x8(const float4 lo, const float4 hi) {
  f16x8 f;
  f[0]=(f16)lo.x; f[1]=(f16)lo.y; f[2]=(f16)lo.z; f[3]=(f16)lo.w;
  f[4]=(f16)hi.x; f[5]=(f16)hi.y; f[6]=(f16)hi.z; f[7]=(f16)hi.w;
  return f;
}

// ---------------------------------------------------------------------------
// Kernel 1: gi[t][b][c] = (x[t,b,:] @ W_ih[r|n,:].T + b_ih[r|n])  as f16
// c in [0,512): c<256 -> i_r col c (W row c); c>=256 -> i_n col c-256 (W row 256+c)
// Stored aliased into d_out (f16 pairs in the f32 slots; exact same byte count).
// Block = 256 rows of the (T*B) row space = half a t-slice. Skips fully-inactive
// blocks (lengths sorted descending).
// ---------------------------------------------------------------------------
__global__ __launch_bounds__(512, 2) void gi_kernel(
    const float* __restrict__ x,
    const int*   __restrict__ lengths,
    const float* __restrict__ w_ih,
    const float* __restrict__ b_ih,
    f16*         __restrict__ gi)
{
  const int m0 = blockIdx.x * 256;
  const int t0 = m0 >> 9;
  const int b0 = m0 & 511;
  if (t0 >= lengths[b0]) return;   // whole block past its longest row: skip

  __shared__ __align__(16) float xs[2][16 * 260];   // 16 rows, padded stride

  const int tid  = threadIdx.x;
  const int wave = tid >> 6;
  const int lane = tid & 63;
  const int cl   = lane & 15;
  const int kq   = lane >> 4;
  const int kk   = kq * 8;

  // resident W_ih fragments: wave owns output cols [wave*64, wave*64+64)
  f16x8 wf[4][8];
  float bias[4];
#pragma unroll
  for (int ct = 0; ct < 4; ++ct) {
    const int c = wave * 64 + ct * 16 + cl;
    const int srow = (c < 256) ? c : (256 + c);
    const float* p = w_ih + (size_t)srow * 256 + kk;
#pragma unroll
    for (int kt = 0; kt < 8; ++kt) {
      float4 lo = *(const float4*)(p + kt * 32);
      float4 hi = *(const float4*)(p + kt * 32 + 4);
      wf[ct][kt] = cvt_f16x8(lo, hi);
    }
    bias[ct] = b_ih[srow];
  }

  uint4 g[2];
  // ---- stage subtile 0
#pragma unroll
  for (int i = 0; i < 2; ++i) {
    int q = i * 512 + tid; int r = q >> 6; int kc = (q & 63) * 4;
    g[i] = *(const uint4*)(x + (size_t)(m0 + r) * 256 + kc);
  }
#pragma unroll
  for (int i = 0; i < 2; ++i) {
    int q = i * 512 + tid; int r = q >> 6; int kc = (q & 63) * 4;
    *(uint4*)(&xs[0][r * 260 + kc]) = g[i];
  }
  __syncthreads();

  for (int ms = 0; ms < 16; ++ms) {
    const int buf = ms & 1;
    const bool more = (ms + 1) < 16;
    if (more) {
#pragma unroll
      for (int i = 0; i < 2; ++i) {
        int q = i * 512 + tid; int r = q >> 6; int kc = (q & 63) * 4;
        g[i] = *(const uint4*)(x + (size_t)(m0 + (ms + 1) * 16 + r) * 256 + kc);
      }
    }
    // compute subtile ms
    f32x4 acc[4];
#pragma unroll
    for (int ct = 0; ct < 4; ++ct) acc[ct] = (f32x4){0.f, 0.f, 0.f, 0.f};
#pragma unroll
    for (int kt = 0; kt < 8; ++kt) {
      const float* hp = &xs[buf][cl * 260 + kt * 32 + kk];
      float4 lo = *(const float4*)(hp);
      float4 hi = *(const float4*)(hp + 4);
      f16x8 a = cvt_f16x8(lo, hi);
#pragma unroll
      for (int ct = 0; ct < 4; ++ct)
        acc[ct] = MFMA16(a, wf[ct][kt], acc[ct]);
    }
    const int rbase = m0 + ms * 16 + kq * 4;
#pragma unroll
    for (int ct = 0; ct < 4; ++ct) {
      const int c = wave * 64 + ct * 16 + cl;
#pragma unroll
      for (int e = 0; e < 4; ++e)
        gi[(size_t)(rbase + e) * 512 + c] = (f16)(acc[ct][e] + bias[ct]);
    }
    if (more) {
#pragma unroll
      for (int i = 0; i < 2; ++i) {
        int q = i * 512 + tid; int r = q >> 6; int kc = (q & 63) * 4;
        *(uint4*)(&xs[buf ^ 1][r * 260 + kc]) = g[i];
      }
    }
    __syncthreads();
  }
}

// ---------------------------------------------------------------------------
// Kernel 2: the recurrence. 32 blocks x 16 batch rows, 8 waves (512 thr).
// W_hh (r+n) resident in registers as MFMA B-frags (128 VGPR/wave, 2 w/SIMD).
// h carried in f32 registers (D-layout) + f16 copy in LDS for next step's
// A-frags. gi[t+1] prefetched (reg-staged) each step. One barrier per step.
// ---------------------------------------------------------------------------
__global__ __launch_bounds__(512, 2) void gru_kernel(
    const float* __restrict__ att,
    const int*   __restrict__ lengths,
    const float* __restrict__ h0,
    const float* __restrict__ w_hh,
    const float* __restrict__ b_hh,
    float*       __restrict__ out)
{
  const f16* gi = (const f16*)out;   // aliased precomputed gi
  const int bb   = blockIdx.x * 16;
  const int Lmax = lengths[bb];      // descending -> max length of this block
  const int tid  = threadIdx.x;
  const int wave = tid >> 6;
  const int lane = tid & 63;
  const int cl   = lane & 15;
  const int kq   = lane >> 4;
  const int kk   = kq * 8;

  __shared__ __align__(16) f16 gis[2][16 * 528];  // row slot sigma(r), stride 528 f16
  __shared__ __align__(16) f16 hs[2][16 * 264];   // padded stride

  // resident W_hh frags: wave owns hidden cols j in [wave*32, wave*32+32)
  f16x8 whr[2][8], whn[2][8];
  float bhr[2], bhn[2];
#pragma unroll
  for (int jt = 0; jt < 2; ++jt) {
    const int j = wave * 32 + jt * 16 + cl;
    const float* pr = w_hh + (size_t)j * 256 + kk;
    const float* pn = w_hh + (size_t)(512 + j) * 256 + kk;
#pragma unroll
    for (int kt = 0; kt < 8; ++kt) {
      float4 lo = *(const float4*)(pr + kt * 32);
      float4 hi = *(const float4*)(pr + kt * 32 + 4);
      whr[jt][kt] = cvt_f16x8(lo, hi);
      lo = *(const float4*)(pn + kt * 32);
      hi = *(const float4*)(pn + kt * 32 + 4);
      whn[jt][kt] = cvt_f16x8(lo, hi);
    }
    bhr[jt] = b_hh[j];
    bhn[jt] = b_hh[512 + j];
  }

  int len_r[4];
#pragma unroll
  for (int e = 0; e < 4; ++e) len_r[e] = lengths[bb + kq * 4 + e];

  // f32 h carry in registers (D-layout), plus initial f16 copy to LDS
  float hc[2][4];
#pragma unroll
  for (int jt = 0; jt < 2; ++jt) {
#pragma unroll
    for (int e = 0; e < 4; ++e) {
      const int r = kq * 4 + e;
      const int j = wave * 32 + jt * 16 + cl;
      hc[jt][e] = h0[(size_t)(bb + r) * 256 + j];
      hs[0][r * 264 + j] = (f16)hc[jt][e];
    }
  }

  // stage gi[0]
#pragma unroll
  for (int i = 0; i < 2; ++i) {
    int q = i * 512 + tid; int r = q >> 6; int cc = (q & 63) * 8;
    int sr = ((r & 3) << 2) | (r >> 2);
    uint4 v = *(const uint4*)(gi + ((size_t)(bb + r)) * 512 + cc);
    *(uint4*)(&gis[0][sr * 528 + cc]) = v;
  }
  __syncthreads();

  int buf = 0;
  uint4 g[2];
  for (int t = 0; t < Lmax; ++t) {
    const bool sn = (t + 1) < Lmax;
    if (sn) {   // issue next-step gi loads early (latency hidden under MFMA)
#pragma unroll
      for (int i = 0; i < 2; ++i) {
        int q = i * 512 + tid; int r = q >> 6; int cc = (q & 63) * 8;
        g[i] = *(const uint4*)(gi + ((size_t)(t + 1) * 512 + bb + r) * 512 + cc);
      }
    }
    float a_r[4];
#pragma unroll
    for (int e = 0; e < 4; ++e) a_r[e] = att[(size_t)t * 512 + bb + kq * 4 + e];

    // gh = h @ W_hh(r|n)^T
    f32x4 ahr[2], ahn[2];
#pragma unroll
    for (int jt = 0; jt < 2; ++jt) {
      ahr[jt] = (f32x4){0.f, 0.f, 0.f, 0.f};
      ahn[jt] = (f32x4){0.f, 0.f, 0.f, 0.f};
    }
#pragma unroll
    for (int kt = 0; kt < 8; ++kt) {
      f16x8 hf = *(const f16x8*)(&hs[buf][cl * 264 + kt * 32 + kk]);
#pragma unroll
      for (int jt = 0; jt < 2; ++jt) {
        ahr[jt] = MFMA16(hf, whr[jt][kt], ahr[jt]);
        ahn[jt] = MFMA16(hf, whn[jt][kt], ahn[jt]);
      }
    }

    // epilogue: gates + attention mix + carry
#pragma unroll
    for (int jt = 0; jt < 2; ++jt) {
      const int j = wave * 32 + jt * 16 + cl;
#pragma unroll
      for (int e = 0; e < 4; ++e) {
        const int r = kq * 4 + e;
        const int sr = ((r & 3) << 2) | (r >> 2);
        float gr = (float)gis[buf][sr * 528 + j];
        float gn = (float)gis[buf][sr * 528 + 256 + j];
        float hrv = ahr[jt][e] + bhr[jt] + gr;
        float hnv = ahn[jt][e] + bhn[jt];
        float rst = __builtin_amdgcn_rcpf(1.f + __expf(-hrv));
        float pre = gn + rst * hnv;
        float ex  = __expf(2.f * pre);
        float ns  = 1.f - 2.f * __builtin_amdgcn_rcpf(ex + 1.f);
        float a   = a_r[e];
        float hy  = hc[jt][e] + a * (ns - hc[jt][e]);
        if (t < len_r[e]) {
          hc[jt][e] = hy;
          out[((size_t)t * 512 + bb + r) * 256 + j] = hy;
        }
        hs[buf ^ 1][r * 264 + j] = (f16)hc[jt][e];
      }
    }

    if (sn) {   // write prefetched gi[t+1] into the other buffer
#pragma unroll
      for (int i = 0; i < 2; ++i) {
        int q = i * 512 + tid; int r = q >> 6; int cc = (q & 63) * 8;
        int sr = ((r & 3) << 2) | (r >> 2);
        *(uint4*)(&gis[buf ^ 1][sr * 528 + cc]) = g[i];
      }
    }
    __syncthreads();
    buf ^= 1;
  }

  // zero tails: out[t][b][:] = 0 for t >= lengths[b]
  const uint4 z4 = make_uint4(0, 0, 0, 0);
  for (int rr = 0; rr < 16; ++rr) {
    const int b = bb + rr;
    const int len = lengths[b];
    const int nchunk = (T_STEPS - len) * 64;   // 64 uint4 per (t,b) row
    for (int z = tid; z < nchunk; z += 512) {
      const int t = len + (z >> 6);
      const int c4 = (z & 63) * 4;
      *(uint4*)(out + ((size_t)t * 512 + b) * 256 + c4) = z4;
    }
  }
}

extern "C" void kernel_launch(void* const* d_in, const int* in_sizes, int n_in,
                              void* d_out, int out_size, void* d_ws, size_t ws_size,
                              hipStream_t stream) {
  const float* x       = (const float*)d_in[0];
  const float* att     = (const float*)d_in[1];
  const int*   lengths = (const int*)d_in[2];
  const float* h0      = (const float*)d_in[3];
  const float* w_ih    = (const float*)d_in[4];
  const float* w_hh    = (const float*)d_in[5];
  const float* b_ih    = (const float*)d_in[6];
  const float* b_hh    = (const float*)d_in[7];
  float* out = (float*)d_out;

  (void)in_sizes; (void)n_in; (void)out_size; (void)d_ws; (void)ws_size;

  hipLaunchKernelGGL(gi_kernel, dim3(400), dim3(512), 0, stream,
                     x, lengths, w_ih, b_ih, (f16*)out);
  hipLaunchKernelGGL(gru_kernel, dim3(32), dim3(512), 0, stream,
                     att, lengths, h0, w_hh, b_hh, out);
}

// Round 2
// 358.420 us; speedup vs baseline: 1.7052x; 1.7052x over previous
//
#include <hip/hip_runtime.h>
#include <hip/hip_fp16.h>
#include <stdint.h>

typedef _Float16 f16;
typedef _Float16 f16x4 __attribute__((ext_vector_type(4)));
typedef _Float16 f16x8 __attribute__((ext_vector_type(8)));
typedef float f32x4 __attribute__((ext_vector_type(4)));

#define T_STEPS 200
#define LOG2E 1.4426950408889634f
#define TWOLOG2E 2.8853900817779268f

#define MFMA16(a,b,c) __builtin_amdgcn_mfma_f32_16x16x32_f16((a),(b),(c),0,0,0)

__device__ __forceinline__ f16x8 cvt_f16x8(const float4 lo, const float4 hi) {
  f16x8 f;
  f[0]=(f16)lo.x; f[1]=(f16)lo.y; f[2]=(f16)lo.z; f[3]=(f16)lo.w;
  f[4]=(f16)hi.x; f[5]=(f16)hi.y; f[6]=(f16)hi.z; f[7]=(f16)hi.w;
  return f;
}
__device__ __forceinline__ f16x4 cvt_f16x4(const float4 v) {
  f16x4 f; f[0]=(f16)v.x; f[1]=(f16)v.y; f[2]=(f16)v.z; f[3]=(f16)v.w; return f;
}
__device__ __forceinline__ void gload_lds16(const void* g, void* l) {
  __builtin_amdgcn_global_load_lds(
      (const __attribute__((address_space(1))) unsigned int*)g,
      (__attribute__((address_space(3))) unsigned int*)l, 16, 0, 0);
}

// ---------------------------------------------------------------------------
// Kernel 1: gi[t][b][c], c in [0,512), stored f16 aliased into d_out.
//   c<256 (r):  -log2(e) * (x@W_r^T + b_ih_r + b_hh_r)   [sigmoid pre-scaled]
//   c>=256 (n):  2*log2(e) * (x@W_n^T + b_ih_n)          [tanh pre-scaled]
// x staged to LDS as f16 (cvt at staging). Wave owns 64 output cols.
// ---------------------------------------------------------------------------
__global__ __launch_bounds__(512, 2) void gi_kernel(
    const float* __restrict__ x,
    const int*   __restrict__ lengths,
    const float* __restrict__ w_ih,
    const float* __restrict__ b_ih,
    const float* __restrict__ b_hh,
    f16*         __restrict__ gi)
{
  const int m0 = blockIdx.x * 256;
  if ((m0 >> 9) >= lengths[m0 & 511]) return;   // whole block past lengths

  __shared__ __align__(16) f16 xs[2][16 * 264];

  const int tid  = threadIdx.x;
  const int wave = tid >> 6;
  const int lane = tid & 63;
  const int cl   = lane & 15;
  const int kq   = lane >> 4;
  const int kk   = kq * 8;
  const float kscale = (wave < 4) ? -LOG2E : TWOLOG2E;

  f16x8 wf[4][8];
  float bias2[4];
#pragma unroll
  for (int ct = 0; ct < 4; ++ct) {
    const int c = wave * 64 + ct * 16 + cl;
    const int srow = (wave < 4) ? c : (256 + c);
    const float* p = w_ih + (size_t)srow * 256 + kk;
#pragma unroll
    for (int kt = 0; kt < 8; ++kt) {
      float4 lo = *(const float4*)(p + kt * 32);
      float4 hi = *(const float4*)(p + kt * 32 + 4);
      wf[ct][kt] = cvt_f16x8(lo, hi);
    }
    bias2[ct] = (wave < 4) ? (b_ih[c] + b_hh[c]) : b_ih[256 + c];
  }

  float4 g[2];
#pragma unroll
  for (int i = 0; i < 2; ++i) {
    int q = i * 512 + tid; int r = q >> 6; int kc = (q & 63) * 4;
    g[i] = *(const float4*)(x + (size_t)(m0 + r) * 256 + kc);
  }
#pragma unroll
  for (int i = 0; i < 2; ++i) {
    int q = i * 512 + tid; int r = q >> 6; int kc = (q & 63) * 4;
    *(f16x4*)(&xs[0][r * 264 + kc]) = cvt_f16x4(g[i]);
  }
  __syncthreads();

  for (int ms = 0; ms < 16; ++ms) {
    const int buf = ms & 1;
    const bool more = (ms + 1) < 16;
    if (more) {
#pragma unroll
      for (int i = 0; i < 2; ++i) {
        int q = i * 512 + tid; int r = q >> 6; int kc = (q & 63) * 4;
        g[i] = *(const float4*)(x + (size_t)(m0 + (ms + 1) * 16 + r) * 256 + kc);
      }
    }
    f32x4 acc[4];
#pragma unroll
    for (int ct = 0; ct < 4; ++ct) acc[ct] = (f32x4){0.f, 0.f, 0.f, 0.f};
#pragma unroll
    for (int kt = 0; kt < 8; ++kt) {
      f16x8 a = *(const f16x8*)(&xs[buf][cl * 264 + kt * 32 + kk]);
#pragma unroll
      for (int ct = 0; ct < 4; ++ct)
        acc[ct] = MFMA16(a, wf[ct][kt], acc[ct]);
    }
    const int rbase = m0 + ms * 16 + kq * 4;
#pragma unroll
    for (int ct = 0; ct < 4; ++ct) {
      const int c = wave * 64 + ct * 16 + cl;
#pragma unroll
      for (int e = 0; e < 4; ++e)
        gi[(size_t)(rbase + e) * 512 + c] = (f16)(kscale * (acc[ct][e] + bias2[ct]));
    }
    if (more) {
#pragma unroll
      for (int i = 0; i < 2; ++i) {
        int q = i * 512 + tid; int r = q >> 6; int kc = (q & 63) * 4;
        *(f16x4*)(&xs[buf ^ 1][r * 264 + kc]) = cvt_f16x4(g[i]);
      }
    }
    __syncthreads();
  }
}

// ---------------------------------------------------------------------------
// Kernel 2: recurrence. 32 blocks x 16 rows, 16 waves (1024 thr, 4/SIMD).
// Wave owns 16 hidden cols (j = wave*16+cl). W_hh r+n resident (64 VGPR).
// gi[t+1] staged via global_load_lds (1 row/wave). att pre-staged in LDS.
// Raw s_barrier with vmcnt(4): stores fly across steps, no barrier drain.
// ---------------------------------------------------------------------------
__global__ __launch_bounds__(1024, 4) void gru_kernel(
    const float* __restrict__ att,
    const int*   __restrict__ lengths,
    const float* __restrict__ h0,
    const float* __restrict__ w_hh,
    const float* __restrict__ b_hh,
    float*       __restrict__ out)
{
  const f16* gi = (const f16*)out;   // aliased precomputed gi
  const int bb   = blockIdx.x * 16;
  const int tid  = threadIdx.x;
  const int w    = tid >> 6;
  const int lane = tid & 63;
  const int cl   = lane & 15;
  const int kq   = lane >> 4;
  const int kk   = kq * 8;
  const int j    = w * 16 + cl;

  __shared__ __align__(16) f16   gis[2][16 * 520];   // stride 520 f16 (1040B, 16B-aligned)
  __shared__ __align__(16) f16   hs[2][16 * 264];
  __shared__ __align__(16) float att_s[T_STEPS * 16];

  const int Lmax = lengths[bb];

  // resident W_hh fragments (r and n rows for col j)
  f16x8 whr[8], whn[8];
  {
    const float* pr = w_hh + (size_t)j * 256 + kk;
    const float* pn = w_hh + (size_t)(512 + j) * 256 + kk;
#pragma unroll
    for (int kt = 0; kt < 8; ++kt) {
      float4 lo = *(const float4*)(pr + kt * 32);
      float4 hi = *(const float4*)(pr + kt * 32 + 4);
      whr[kt] = cvt_f16x8(lo, hi);
      lo = *(const float4*)(pn + kt * 32);
      hi = *(const float4*)(pn + kt * 32 + 4);
      whn[kt] = cvt_f16x8(lo, hi);
    }
  }
  const float bhn2 = TWOLOG2E * b_hh[512 + j];

  int len_r[4];
#pragma unroll
  for (int e = 0; e < 4; ++e) len_r[e] = lengths[bb + kq * 4 + e];

  // stage att for this block: [t][16] floats
  for (int i = tid; i < T_STEPS * 4; i += 1024) {
    int t = i >> 2, c = (i & 3) * 4;
    *(float4*)(&att_s[t * 16 + c]) = *(const float4*)(att + (size_t)t * 512 + bb + c);
  }

  // h carry (f32 regs) + f16 copy to LDS
  float hc[4];
#pragma unroll
  for (int e = 0; e < 4; ++e) {
    const int r = kq * 4 + e;
    hc[e] = h0[(size_t)(bb + r) * 256 + j];
    hs[0][r * 264 + j] = (f16)hc[e];
  }

  // stage gi[0]: wave w stages row w
  gload_lds16(gi + ((size_t)(bb + w)) * 512 + lane * 8, &gis[0][w * 520]);
  __syncthreads();

  int buf = 0;
  for (int t = 0; t < Lmax; ++t) {
    const int nb = buf ^ 1;
    if (t + 1 < Lmax)   // wave-uniform branch (Lmax uniform per block)
      gload_lds16(gi + ((size_t)(t + 1) * 512 + bb + w) * 512 + lane * 8,
                  &gis[nb][w * 520]);

    // gh = h @ W_hh(r|n)^T ; two depth-4 chains per gate
    f32x4 ar0 = (f32x4){0.f,0.f,0.f,0.f}, ar1 = ar0, an0 = ar0, an1 = ar0;
#pragma unroll
    for (int kt = 0; kt < 4; ++kt) {
      f16x8 hf = *(const f16x8*)(&hs[buf][cl * 264 + kt * 32 + kk]);
      ar0 = MFMA16(hf, whr[kt], ar0);
      an0 = MFMA16(hf, whn[kt], an0);
    }
#pragma unroll
    for (int kt = 4; kt < 8; ++kt) {
      f16x8 hf = *(const f16x8*)(&hs[buf][cl * 264 + kt * 32 + kk]);
      ar1 = MFMA16(hf, whr[kt], ar1);
      an1 = MFMA16(hf, whn[kt], an1);
    }
    const f32x4 ahr = ar0 + ar1;
    const f32x4 ahn = an0 + an1;

    float4 a4 = *(const float4*)(&att_s[t * 16 + kq * 4]);
    float av[4] = {a4.x, a4.y, a4.z, a4.w};

#pragma unroll
    for (int e = 0; e < 4; ++e) {
      const int r = kq * 4 + e;
      float gr = (float)gis[buf][r * 520 + j];        // -log2e*(i_r + biases)
      float gn = (float)gis[buf][r * 520 + 256 + j];  // 2log2e*(i_n + b_ih)
      float e2  = __builtin_amdgcn_exp2f(fmaf(ahr[e], -LOG2E, gr));
      float rst = __builtin_amdgcn_rcpf(1.f + e2);
      float hnv = fmaf(ahn[e], TWOLOG2E, bhn2);
      float q2  = fmaf(rst, hnv, gn);
      float en  = __builtin_amdgcn_exp2f(q2);
      float ns  = fmaf(-2.f, __builtin_amdgcn_rcpf(1.f + en), 1.f);
      float hy  = fmaf(av[e], ns - hc[e], hc[e]);
      out[((size_t)t * 512 + bb + r) * 256 + j] = hy;   // unconditional (vmcnt count!)
      if (t < len_r[e]) hc[e] = hy;                     // carry guarded
      hs[nb][r * 264 + j] = (f16)hc[e];
    }

    // counted wait: 1 gload_lds (oldest) + 4 stores in flight -> vmcnt(4)
    // retires exactly the gload; stores drain during next step.
    asm volatile("s_waitcnt vmcnt(4) lgkmcnt(0)" ::: "memory");
    __builtin_amdgcn_s_barrier();
    __builtin_amdgcn_sched_barrier(0);
    buf = nb;
  }

  __syncthreads();   // full drain: loop's garbage stores (t>=len) must land first

  // zero tails: out[t][b][:] = 0 for t >= lengths[b]
  const uint4 z4 = make_uint4(0, 0, 0, 0);
  for (int rr = 0; rr < 16; ++rr) {
    const int b = bb + rr;
    const int len = lengths[b];
    const int nchunk = (T_STEPS - len) * 64;   // 64 uint4 per (t,b) row
    for (int z = tid; z < nchunk; z += 1024) {
      const int t = len + (z >> 6);
      const int c4 = (z & 63) * 4;
      *(uint4*)(out + ((size_t)t * 512 + b) * 256 + c4) = z4;
    }
  }
}

extern "C" void kernel_launch(void* const* d_in, const int* in_sizes, int n_in,
                              void* d_out, int out_size, void* d_ws, size_t ws_size,
                              hipStream_t stream) {
  const float* x       = (const float*)d_in[0];
  const float* att     = (const float*)d_in[1];
  const int*   lengths = (const int*)d_in[2];
  const float* h0      = (const float*)d_in[3];
  const float* w_ih    = (const float*)d_in[4];
  const float* w_hh    = (const float*)d_in[5];
  const float* b_ih    = (const float*)d_in[6];
  const float* b_hh    = (const float*)d_in[7];
  float* out = (float*)d_out;

  (void)in_sizes; (void)n_in; (void)out_size; (void)d_ws; (void)ws_size;

  hipLaunchKernelGGL(gi_kernel, dim3(400), dim3(512), 0, stream,
                     x, lengths, w_ih, b_ih, b_hh, (f16*)out);
  hipLaunchKernelGGL(gru_kernel, dim3(32), dim3(1024), 0, stream,
                     att, lengths, h0, w_hh, b_hh, out);
}